// Round 1
// baseline (1339.663 us; speedup 1.0000x reference)
//
#include <hip/hip_runtime.h>

// Kuramoto phase dynamics + coherence softmax.
// B=4, S=256 -> 1024 rows; V=50257 per row; 10 steps.
// One 1024-thread block per row; phases held in registers (p[50] per thread).

#define V_DIM 50257
#define NROWS 1024
#define NTHREADS 1024
#define NPT 50            // ceil(50257/1024)
#define N_STEPS 10

__device__ __forceinline__ void block_reduce2(float& a, float& b, float* lds) {
    // 64-lane wave butterfly
    #pragma unroll
    for (int off = 32; off > 0; off >>= 1) {
        a += __shfl_xor(a, off, 64);
        b += __shfl_xor(b, off, 64);
    }
    const int wid  = threadIdx.x >> 6;   // 16 waves
    const int lane = threadIdx.x & 63;
    if (lane == 0) { lds[wid] = a; lds[16 + wid] = b; }
    __syncthreads();
    float ta = 0.f, tb = 0.f;
    #pragma unroll
    for (int i = 0; i < NTHREADS / 64; ++i) { ta += lds[i]; tb += lds[16 + i]; }
    __syncthreads();   // protect lds before next reuse
    a = ta; b = tb;
}

__global__ __launch_bounds__(NTHREADS, 4)
void kuramoto_kernel(const float* __restrict__ logits,
                     const float* __restrict__ omega,
                     const float* __restrict__ noise,
                     float* __restrict__ out) {
    const int row = blockIdx.x;
    const int tid = threadIdx.x;
    const size_t base = (size_t)row * V_DIM;
    const float* __restrict__ lg = logits + base;
    const float* __restrict__ nz = noise + base;
    float* __restrict__ op = out + base;

    __shared__ float lds[32];

    const float coup = 0.1f / (float)V_DIM;   // KURAMOTO_COUPLING / V
    const float dt   = 0.1f;
    const float dtc  = dt * coup;

    // init: phases = noise + 0.1*logits
    float p[NPT];
    #pragma unroll
    for (int k = 0; k < NPT; ++k) {
        const int idx = tid + k * NTHREADS;
        p[k] = (idx < V_DIM) ? (nz[idx] + 0.1f * lg[idx]) : 0.f;
    }

    for (int st = 0; st < N_STEPS; ++st) {
        float ss = 0.f, cc = 0.f;
        #pragma unroll
        for (int k = 0; k < NPT; ++k) {
            const int idx = tid + k * NTHREADS;
            if (idx < V_DIM) {
                ss += __sinf(p[k]);
                cc += __cosf(p[k]);
            }
        }
        block_reduce2(ss, cc, lds);   // ss = sum sin, cc = sum cos (row-wide)

        #pragma unroll
        for (int k = 0; k < NPT; ++k) {
            const int idx = tid + k * NTHREADS;
            if (idx < V_DIM) {
                const float s = __sinf(p[k]);
                const float c = __cosf(p[k]);
                const float w = omega[idx];
                p[k] += dt * w + dtc * (s * cc - c * ss);
            }
        }
    }

    // mean(phases)
    float psum = 0.f, dummy = 0.f;
    #pragma unroll
    for (int k = 0; k < NPT; ++k) {
        const int idx = tid + k * NTHREADS;
        if (idx < V_DIM) psum += p[k];
    }
    block_reduce2(psum, dummy, lds);
    const float mean = psum / (float)V_DIM;

    // coherence = cos(p - mean); softmax over row (exp without max-sub is safe, coh in [-1,1])
    float esum = 0.f, dummy2 = 0.f;
    #pragma unroll
    for (int k = 0; k < NPT; ++k) {
        const int idx = tid + k * NTHREADS;
        if (idx < V_DIM) {
            const float coh = __cosf(p[k] - mean);
            p[k] = coh;
            esum += __expf(coh);
        }
    }
    block_reduce2(esum, dummy2, lds);
    const float inv = 1.f / esum;

    #pragma unroll
    for (int k = 0; k < NPT; ++k) {
        const int idx = tid + k * NTHREADS;
        if (idx < V_DIM) op[idx] = __expf(p[k]) * inv;
    }
}

extern "C" void kernel_launch(void* const* d_in, const int* in_sizes, int n_in,
                              void* d_out, int out_size, void* d_ws, size_t ws_size,
                              hipStream_t stream) {
    const float* logits = (const float*)d_in[0];
    const float* omega  = (const float*)d_in[1];  // natural_frequencies [V]
    const float* noise  = (const float*)d_in[2];
    float* out = (float*)d_out;

    kuramoto_kernel<<<NROWS, NTHREADS, 0, stream>>>(logits, omega, noise, out);
}

// Round 2
// 555.619 us; speedup vs baseline: 2.4111x; 2.4111x over previous
//
#include <hip/hip_runtime.h>

// Kuramoto phase dynamics + coherence softmax.
// B=4, S=256 -> 1024 rows; V=50257 per row; 10 steps.
// One 1024-thread block per row. Phase state kept on-chip:
//   - 20 elems/thread in registers (p[20], plus cached dt*omega)
//   - 30 elems/thread in LDS (120 KiB, [k][tid] layout -> thread-private,
//     conflict-free scalar ds_read/write, no barriers needed)
// amdgpu_waves_per_eu(4,4): 120 KiB LDS means 1 block/CU (16 waves = 4/EU),
// so let the allocator use up to 128 VGPRs instead of spilling at 64.

#define V_DIM    50257
#define NROWS    1024
#define NTHREADS 1024
#define NREG     20
#define NLDS     30
#define N_STEPS  10

__device__ __forceinline__ void block_reduce2(float& a, float& b, float* red) {
    #pragma unroll
    for (int off = 32; off > 0; off >>= 1) {
        a += __shfl_xor(a, off, 64);
        b += __shfl_xor(b, off, 64);
    }
    const int wid = threadIdx.x >> 6;   // 16 waves
    if ((threadIdx.x & 63) == 0) { red[wid] = a; red[16 + wid] = b; }
    __syncthreads();
    float ta = 0.f, tb = 0.f;
    #pragma unroll
    for (int i = 0; i < NTHREADS / 64; ++i) { ta += red[i]; tb += red[16 + i]; }
    __syncthreads();
    a = ta; b = tb;
}

__global__ __attribute__((amdgpu_waves_per_eu(4, 4))) __launch_bounds__(NTHREADS)
void kuramoto_kernel(const float* __restrict__ logits,
                     const float* __restrict__ omega,
                     const float* __restrict__ noise,
                     float* __restrict__ out) {
    __shared__ float pl[NLDS][NTHREADS];   // 120 KiB, thread-private columns
    __shared__ float red[32];

    const int row = blockIdx.x;
    const int tid = threadIdx.x;
    const size_t base = (size_t)row * V_DIM;
    const float* __restrict__ lg = logits + base;
    const float* __restrict__ nz = noise + base;
    float* __restrict__ op = out + base;

    const float dtc = 0.1f * (0.1f / (float)V_DIM);   // DT * coupling

    // init: phases = noise + 0.1*logits ; cache dt*omega for register elems
    float p[NREG], wr[NREG];
    #pragma unroll
    for (int k = 0; k < NREG; ++k) {
        const int idx = tid + k * NTHREADS;           // max 20479 < V_DIM
        p[k]  = nz[idx] + 0.1f * lg[idx];
        wr[k] = 0.1f * omega[idx];
    }
    #pragma unroll
    for (int k = 0; k < NLDS; ++k) {
        const int idx = tid + (NREG + k) * NTHREADS;
        if (idx < V_DIM) pl[k][tid] = nz[idx] + 0.1f * lg[idx];
    }

    for (int st = 0; st < N_STEPS; ++st) {
        float ss = 0.f, cc = 0.f;
        #pragma unroll
        for (int k = 0; k < NREG; ++k) {
            ss += __sinf(p[k]);
            cc += __cosf(p[k]);
        }
        #pragma unroll
        for (int k = 0; k < NLDS; ++k) {
            const int idx = tid + (NREG + k) * NTHREADS;
            if (idx < V_DIM) {
                const float ph = pl[k][tid];
                ss += __sinf(ph);
                cc += __cosf(ph);
            }
        }
        block_reduce2(ss, cc, red);   // row-wide sum(sin), sum(cos)

        #pragma unroll
        for (int k = 0; k < NREG; ++k) {
            const float s = __sinf(p[k]);
            const float c = __cosf(p[k]);
            p[k] += wr[k] + dtc * (s * cc - c * ss);
        }
        #pragma unroll
        for (int k = 0; k < NLDS; ++k) {
            const int idx = tid + (NREG + k) * NTHREADS;
            if (idx < V_DIM) {
                const float ph = pl[k][tid];
                const float s = __sinf(ph);
                const float c = __cosf(ph);
                pl[k][tid] = ph + 0.1f * omega[idx] + dtc * (s * cc - c * ss);
            }
        }
    }

    // mean(phases)
    float psum = 0.f, d0 = 0.f;
    #pragma unroll
    for (int k = 0; k < NREG; ++k) psum += p[k];
    #pragma unroll
    for (int k = 0; k < NLDS; ++k) {
        const int idx = tid + (NREG + k) * NTHREADS;
        if (idx < V_DIM) psum += pl[k][tid];
    }
    block_reduce2(psum, d0, red);
    const float mean = psum / (float)V_DIM;

    // e = exp(cos(p - mean)); store e in place, reduce the sum
    float esum = 0.f, d1 = 0.f;
    #pragma unroll
    for (int k = 0; k < NREG; ++k) {
        const float e = __expf(__cosf(p[k] - mean));
        p[k] = e;
        esum += e;
    }
    #pragma unroll
    for (int k = 0; k < NLDS; ++k) {
        const int idx = tid + (NREG + k) * NTHREADS;
        if (idx < V_DIM) {
            const float e = __expf(__cosf(pl[k][tid] - mean));
            pl[k][tid] = e;
            esum += e;
        }
    }
    block_reduce2(esum, d1, red);
    const float inv = 1.f / esum;

    #pragma unroll
    for (int k = 0; k < NREG; ++k) {
        const int idx = tid + k * NTHREADS;
        op[idx] = p[k] * inv;
    }
    #pragma unroll
    for (int k = 0; k < NLDS; ++k) {
        const int idx = tid + (NREG + k) * NTHREADS;
        if (idx < V_DIM) op[idx] = pl[k][tid] * inv;
    }
}

extern "C" void kernel_launch(void* const* d_in, const int* in_sizes, int n_in,
                              void* d_out, int out_size, void* d_ws, size_t ws_size,
                              hipStream_t stream) {
    const float* logits = (const float*)d_in[0];
    const float* omega  = (const float*)d_in[1];  // natural_frequencies [V]
    const float* noise  = (const float*)d_in[2];
    float* out = (float*)d_out;
    (void)d_ws; (void)ws_size; (void)in_sizes; (void)n_in; (void)out_size;

    kuramoto_kernel<<<NROWS, NTHREADS, 0, stream>>>(logits, omega, noise, out);
}